// Round 2
// baseline (783.982 us; speedup 1.0000x reference)
//
#include <hip/hip_runtime.h>

static constexpr int ID = 128;   // IN_DIM
static constexpr int ND = 32;    // NET_DIM

// ---- deg count: one int atomic per edge at target ----
__global__ __launch_bounds__(256) void k_count(const int* __restrict__ col, int E,
                                               unsigned* __restrict__ cnt) {
    int e = blockIdx.x * 256 + threadIdx.x;
    if (e < E) atomicAdd(&cnt[col[e]], 1u);
}

// ---- per-block sums of cnt (256 elems/block) ----
__global__ __launch_bounds__(256) void k_blocksum(const unsigned* __restrict__ cnt, int n,
                                                  unsigned* __restrict__ bsum) {
    __shared__ unsigned s[256];
    int i = blockIdx.x * 256 + threadIdx.x;
    s[threadIdx.x] = (i < n) ? cnt[i] : 0u;
    __syncthreads();
    for (int d = 128; d > 0; d >>= 1) {
        if (threadIdx.x < d) s[threadIdx.x] += s[threadIdx.x + d];
        __syncthreads();
    }
    if (threadIdx.x == 0) bsum[blockIdx.x] = s[0];
}

// ---- exclusive scan of block sums (single block, up to 512 blocks) ----
__global__ __launch_bounds__(512) void k_scanblocks(const unsigned* __restrict__ bsum, int nb,
                                                    unsigned* __restrict__ boff) {
    __shared__ unsigned s[512];
    int t = threadIdx.x;
    unsigned v0 = (t < nb) ? bsum[t] : 0u;
    s[t] = v0;
    __syncthreads();
    for (int d = 1; d < 512; d <<= 1) {
        unsigned v = (t >= d) ? s[t - d] : 0u;
        __syncthreads();
        s[t] += v;
        __syncthreads();
    }
    if (t < nb) boff[t] = s[t] - v0;   // exclusive
}

// ---- cursor[i] = global exclusive scan of cnt; dinv = rsqrt(cnt+1) ----
__global__ __launch_bounds__(256) void k_mkcursor(const unsigned* __restrict__ cnt, int n,
                                                  const unsigned* __restrict__ boff,
                                                  unsigned* __restrict__ cursor,
                                                  float* __restrict__ dinv) {
    __shared__ unsigned s[256];
    int i = blockIdx.x * 256 + threadIdx.x;
    unsigned v0 = (i < n) ? cnt[i] : 0u;
    s[threadIdx.x] = v0;
    __syncthreads();
    for (int d = 1; d < 256; d <<= 1) {
        unsigned v = (threadIdx.x >= (unsigned)d) ? s[threadIdx.x - d] : 0u;
        __syncthreads();
        s[threadIdx.x] += v;
        __syncthreads();
    }
    if (i < n) {
        cursor[i] = boff[blockIdx.x] + s[threadIdx.x] - v0;   // exclusive
        dinv[i] = rsqrtf((float)(v0 + 1u));
    }
}

// ---- fill CSR: srclist[pos] = row, pos = cursor[col]++ ----
__global__ __launch_bounds__(256) void k_fill(const int* __restrict__ row,
                                              const int* __restrict__ col,
                                              unsigned* __restrict__ cursor,
                                              unsigned* __restrict__ srclist, int E) {
    int e = blockIdx.x * 256 + threadIdx.x;
    if (e < E) {
        unsigned p = atomicAdd(&cursor[col[e]], 1u);
        srclist[p] = (unsigned)row[e];
    }
}

// ---- hs = dinv[i] * (x[i] @ W_gcn) ----
__global__ __launch_bounds__(256) void k_gemm(const float* __restrict__ x,
                                              const float* __restrict__ W,
                                              const float* __restrict__ dinv,
                                              float* __restrict__ hs, int n) {
    __shared__ float sW[ID * ND];        // 16 KB, [k][j]
    for (int i = threadIdx.x; i < ID * ND; i += 256) sW[i] = W[i];
    __syncthreads();
    int row = blockIdx.x * 256 + threadIdx.x;
    if (row >= n) return;
    float acc[ND];
#pragma unroll
    for (int j = 0; j < ND; ++j) acc[j] = 0.f;
    const float4* xr = reinterpret_cast<const float4*>(x + (size_t)row * ID);
    for (int k4 = 0; k4 < ID / 4; ++k4) {
        float4 v = xr[k4];
        const float* w0 = &sW[(k4 * 4 + 0) * ND];
        const float* w1 = &sW[(k4 * 4 + 1) * ND];
        const float* w2 = &sW[(k4 * 4 + 2) * ND];
        const float* w3 = &sW[(k4 * 4 + 3) * ND];
#pragma unroll
        for (int j = 0; j < ND; ++j)
            acc[j] += v.x * w0[j] + v.y * w1[j] + v.z * w2[j] + v.w * w3[j];
    }
    float di = dinv[row];
    float4* hp = reinterpret_cast<float4*>(hs + (size_t)row * ND);
#pragma unroll
    for (int q = 0; q < ND / 4; ++q) {
        float4 o;
        o.x = di * acc[q * 4 + 0];
        o.y = di * acc[q * 4 + 1];
        o.z = di * acc[q * 4 + 2];
        o.w = di * acc[q * 4 + 3];
        hp[q] = o;
    }
}

// ---- gather + finalize: one wave per node ----
// acc[ch] = hs[c][ch] (self loop) + sum over incoming edges hs[src][ch]
// g = relu(dinv[c]*acc + bg); out = relu(g @ Wd + bd)
__global__ __launch_bounds__(256) void k_gather(const unsigned* __restrict__ cursor, // END offsets (post-fill)
                                                const unsigned* __restrict__ cnt,
                                                const unsigned* __restrict__ srclist,
                                                const float* __restrict__ hs,
                                                const float* __restrict__ dinv,
                                                const float* __restrict__ bg,
                                                const float* __restrict__ Wd,
                                                const float* __restrict__ bd,
                                                float* __restrict__ out,
                                                int n, int nwaves_total) {
    __shared__ float sW[ND * ND];   // 4 KB
    __shared__ float sbg[ND];
    __shared__ float sbd[ND];
    for (int i = threadIdx.x; i < ND * ND; i += 256) sW[i] = Wd[i];
    if (threadIdx.x < ND) {
        sbg[threadIdx.x] = bg[threadIdx.x];
        sbd[threadIdx.x] = bd[threadIdx.x];
    }
    __syncthreads();
    int wid = (int)((blockIdx.x * 256 + threadIdx.x) >> 6);
    int lane = threadIdx.x & 63;
    int half = lane >> 5;          // two edges processed per iteration
    int ch = lane & 31;            // channel owned by this lane
    for (int c = wid; c < n; c += nwaves_total) {
        unsigned end = cursor[c];
        unsigned deg = cnt[c];
        unsigned start = end - deg;
        float acc = (half == 0) ? hs[(size_t)c * ND + ch] : 0.f;  // self-loop term
        for (unsigned j = start + (unsigned)half; j < end; j += 2u) {
            unsigned r = srclist[j];            // broadcast within half-wave
            acc += hs[(size_t)r * ND + ch];     // 128B contiguous per half-wave
        }
        acc += __shfl_xor(acc, 32);             // combine halves
        float g = fmaxf(dinv[c] * acc + sbg[ch], 0.f);
        float o = sbd[ch];
#pragma unroll
        for (int j = 0; j < ND; ++j) {
            float gj = __shfl(g, j, 32);        // broadcast g[j] within 32-group
            o += gj * sW[j * ND + ch];
        }
        o = fmaxf(o, 0.f);
        if (half == 0) out[(size_t)c * ND + ch] = o;
    }
}

extern "C" void kernel_launch(void* const* d_in, const int* in_sizes, int n_in,
                              void* d_out, int out_size, void* d_ws, size_t ws_size,
                              hipStream_t stream) {
    const float* x  = (const float*)d_in[0];
    const int*   ei = (const int*)d_in[1];   // [2, E] flat: row then col
    const float* Wg = (const float*)d_in[2];
    const float* bg = (const float*)d_in[3];
    const float* Wd = (const float*)d_in[4];
    const float* bd = (const float*)d_in[5];
    float* out = (float*)d_out;

    const int n = in_sizes[0] / ID;      // 100000
    const int E = in_sizes[1] / 2;       // 3200000
    const int* erow = ei;
    const int* ecol = ei + E;
    const int nb = (n + 255) / 256;      // 391 blocks

    // workspace carve-up
    float*    hs      = (float*)d_ws;                           // n*ND f32   (12.8 MB)
    unsigned* srclist = (unsigned*)(hs + (size_t)n * ND);       // E u32      (12.8 MB)
    unsigned* cnt     = srclist + (size_t)E;                    // n u32
    unsigned* cursor  = cnt + n;                                // n u32
    float*    dinv    = (float*)(cursor + n);                   // n f32
    unsigned* bsum    = (unsigned*)(dinv + n);                  // nb u32
    unsigned* boff    = bsum + nb;                              // nb u32

    hipMemsetAsync(cnt, 0, (size_t)n * sizeof(unsigned), stream);
    k_count<<<(E + 255) / 256, 256, 0, stream>>>(ecol, E, cnt);
    k_blocksum<<<nb, 256, 0, stream>>>(cnt, n, bsum);
    k_scanblocks<<<1, 512, 0, stream>>>(bsum, nb, boff);
    k_mkcursor<<<nb, 256, 0, stream>>>(cnt, n, boff, cursor, dinv);
    k_fill<<<(E + 255) / 256, 256, 0, stream>>>(erow, ecol, cursor, srclist, E);
    k_gemm<<<nb, 256, 0, stream>>>(x, Wg, dinv, hs, n);
    // after k_fill, cursor[c] == end offset of node c's segment
    const int gblocks = 2048;
    k_gather<<<gblocks, 256, 0, stream>>>(cursor, cnt, srclist, hs, dinv,
                                          bg, Wd, bd, out, n, gblocks * 4);
}